// Round 1
// baseline (126.456 us; speedup 1.0000x reference)
//
#include <hip/hip_runtime.h>
#include <math.h>

// Problem constants (fixed by setup_inputs):
// x: [B=2, C=8, T=8, D=64, H=128, W=128] float32
constexpr int BC = 16;                 // B*C
constexpr int T  = 8,  D  = 64, H  = 128, W  = 128;
constexpr int To = 4,  Do = 32, Ho = 64,  Wo = 64;
constexpr int WQ = Wo / 2;             // each thread handles 2 output windows along W
constexpr long long N0 = (long long)BC * To * Do * Ho * Wo;  // x_pool elems   (8388608)
constexpr long long N1 = (long long)BC * T  * Do * Ho * Wo;  // inds_spatial   (16777216)
constexpr long long TOTAL_THREADS = (long long)BC * To * Do * Ho * WQ; // 4194304

__global__ __launch_bounds__(256)
void pool3d_fused_kernel(const float* __restrict__ x,
                         float* __restrict__ xpool,   // [BC,To,Do,Ho,Wo] f32
                         float* __restrict__ sidx,    // [BC,T ,Do,Ho,Wo] idx-as-f32
                         float* __restrict__ tidx)    // [BC,To,Do,Ho,Wo] idx-as-f32
{
    const long long tid = (long long)blockIdx.x * 256 + threadIdx.x;
    if (tid >= TOTAL_THREADS) return;

    int wq = (int)(tid % WQ);
    long long r = tid / WQ;
    const int ho = (int)(r % Ho); r /= Ho;
    const int dd = (int)(r % Do); r /= Do;
    const int to = (int)(r % To); r /= To;
    const int bc = (int)r;

    // Spatial-pool results for the two temporal slices, two windows each.
    float sv[2][2];
    int   si[2][2];

    #pragma unroll
    for (int j = 0; j < 2; ++j) {
        const int t = 2 * to + j;
        float b0 = -INFINITY, b1 = -INFINITY;
        int   i0 = 0,          i1 = 0;
        #pragma unroll
        for (int kd = 0; kd < 2; ++kd) {
            const int d = 2 * dd + kd;
            #pragma unroll
            for (int kh = 0; kh < 2; ++kh) {
                const int h = 2 * ho + kh;
                const long long off =
                    ((((long long)bc * T + t) * D + d) * H + h) * (long long)W + 4 * wq;
                const float4 v = *reinterpret_cast<const float4*>(x + off);
                const int ib = (d * H + h) * W + 4 * wq;  // flat idx into D*H*W
                // first-max scan order: kd, kh, kw -> strict '>' keeps first max
                if (v.x > b0) { b0 = v.x; i0 = ib;     }
                if (v.y > b0) { b0 = v.y; i0 = ib + 1; }
                if (v.z > b1) { b1 = v.z; i1 = ib + 2; }
                if (v.w > b1) { b1 = v.w; i1 = ib + 3; }
            }
        }
        sv[j][0] = b0; sv[j][1] = b1;
        si[j][0] = i0; si[j][1] = i1;

        // inds_spatial write for this t (coalesced float2)
        const long long so =
            ((((long long)bc * T + t) * Do + dd) * Ho + ho) * (long long)Wo + 2 * wq;
        *reinterpret_cast<float2*>(sidx + so) =
            make_float2((float)i0, (float)i1);
    }

    // Temporal pool (k=2, first-max: tie keeps t0 -> strict '>')
    const int kt0 = (sv[1][0] > sv[0][0]) ? 1 : 0;
    const int kt1 = (sv[1][1] > sv[0][1]) ? 1 : 0;
    const float v0 = kt0 ? sv[1][0] : sv[0][0];
    const float v1 = kt1 ? sv[1][1] : sv[0][1];

    const long long oo =
        ((((long long)bc * To + to) * Do + dd) * Ho + ho) * (long long)Wo + 2 * wq;
    *reinterpret_cast<float2*>(xpool + oo) = make_float2(v0, v1);
    *reinterpret_cast<float2*>(tidx  + oo) =
        make_float2((float)(2 * to + kt0), (float)(2 * to + kt1));
}

extern "C" void kernel_launch(void* const* d_in, const int* in_sizes, int n_in,
                              void* d_out, int out_size, void* d_ws, size_t ws_size,
                              hipStream_t stream) {
    const float* x = (const float*)d_in[0];
    float* out0 = (float*)d_out;          // x_pool        [BC,To,Do,Ho,Wo]
    float* out1 = out0 + N0;              // inds_spatial  [BC,T ,Do,Ho,Wo]
    float* out2 = out1 + N1;              // inds_temporal [BC,To,Do*Ho*Wo]

    const int block = 256;
    const int grid  = (int)((TOTAL_THREADS + block - 1) / block);  // 16384
    pool3d_fused_kernel<<<grid, block, 0, stream>>>(x, out0, out1, out2);
}

// Round 3
// 125.788 us; speedup vs baseline: 1.0053x; 1.0053x over previous
//
#include <hip/hip_runtime.h>
#include <math.h>

// x: [B=2, C=8, T=8, D=64, H=128, W=128] float32
constexpr int BC = 16;                 // B*C
constexpr int T  = 8,  D  = 64, H  = 128, W  = 128;
constexpr int To = 4,  Do = 32, Ho = 64,  Wo = 64;
constexpr int WE = Wo / 4;             // each thread handles 4 output windows along W
constexpr int N0 = BC * To * Do * Ho * Wo;   // x_pool elems   (8388608)
constexpr int N1 = BC * T  * Do * Ho * Wo;   // inds_spatial   (16777216)
constexpr int TOTAL_THREADS = BC * To * Do * Ho * WE;  // 2097152

typedef float f32x4 __attribute__((ext_vector_type(4)));  // native vector type
                                                          // (nontemporal builtins
                                                          //  reject HIP_vector_type)

__global__ __launch_bounds__(256)
void pool3d_fused_kernel(const float* __restrict__ x,
                         float* __restrict__ xpool,   // [BC,To,Do,Ho,Wo] f32
                         float* __restrict__ sidx,    // [BC,T ,Do,Ho,Wo] idx-as-f32
                         float* __restrict__ tidx)    // [BC,To,Do,Ho,Wo] idx-as-f32
{
    const int tid = blockIdx.x * 256 + threadIdx.x;   // grid is exact

    const int we = tid & (WE - 1);
    int r = tid / WE;
    const int ho = r & (Ho - 1); r /= Ho;
    const int dd = r & (Do - 1); r /= Do;
    const int to = r & (To - 1); r /= To;
    const int bc = r;

    const int col = 8 * we;       // first input column this thread covers

    // Per t-slice spatial-pool results: 4 windows each.
    float sv[2][4];

    #pragma unroll
    for (int j = 0; j < 2; ++j) {
        const int t = 2 * to + j;
        float bv0 = -INFINITY, bv1 = -INFINITY, bv2 = -INFINITY, bv3 = -INFINITY;
        int   bi0 = 0, bi1 = 0, bi2 = 0, bi3 = 0;
        const int tbase = ((bc * T + t) * D) * H * W;   // fits in int32 (max 2^27)
        #pragma unroll
        for (int kd = 0; kd < 2; ++kd) {
            const int d = 2 * dd + kd;
            #pragma unroll
            for (int kh = 0; kh < 2; ++kh) {
                const int h   = 2 * ho + kh;
                const int off = tbase + (d * H + h) * W + col;
                const f32x4 a = __builtin_nontemporal_load(
                    reinterpret_cast<const f32x4*>(x + off));
                const f32x4 b = __builtin_nontemporal_load(
                    reinterpret_cast<const f32x4*>(x + off + 4));
                const int ib = (d * H + h) * W + col;   // flat idx into D*H*W
                // first-max scan order kd,kh,kw -> strict '>' keeps first max
                if (a.x > bv0) { bv0 = a.x; bi0 = ib;     }
                if (a.y > bv0) { bv0 = a.y; bi0 = ib + 1; }
                if (a.z > bv1) { bv1 = a.z; bi1 = ib + 2; }
                if (a.w > bv1) { bv1 = a.w; bi1 = ib + 3; }
                if (b.x > bv2) { bv2 = b.x; bi2 = ib + 4; }
                if (b.y > bv2) { bv2 = b.y; bi2 = ib + 5; }
                if (b.z > bv3) { bv3 = b.z; bi3 = ib + 6; }
                if (b.w > bv3) { bv3 = b.w; bi3 = ib + 7; }
            }
        }
        sv[j][0] = bv0; sv[j][1] = bv1; sv[j][2] = bv2; sv[j][3] = bv3;

        // inds_spatial write for this t (coalesced 16B nontemporal)
        const int so = (((bc * T + t) * Do + dd) * Ho + ho) * Wo + 4 * we;
        f32x4 siv;
        siv.x = (float)bi0; siv.y = (float)bi1;
        siv.z = (float)bi2; siv.w = (float)bi3;
        __builtin_nontemporal_store(siv, reinterpret_cast<f32x4*>(sidx + so));
    }

    // Temporal pool (k=2; jnp.argmax tie keeps t0 -> strict '>')
    f32x4 ov, ot;
    #pragma unroll
    for (int w = 0; w < 4; ++w) {
        const int kt = (sv[1][w] > sv[0][w]) ? 1 : 0;
        ov[w] = kt ? sv[1][w] : sv[0][w];
        ot[w] = (float)(2 * to + kt);
    }

    const int oo = (((bc * To + to) * Do + dd) * Ho + ho) * Wo + 4 * we;
    __builtin_nontemporal_store(ov, reinterpret_cast<f32x4*>(xpool + oo));
    __builtin_nontemporal_store(ot, reinterpret_cast<f32x4*>(tidx + oo));
}

extern "C" void kernel_launch(void* const* d_in, const int* in_sizes, int n_in,
                              void* d_out, int out_size, void* d_ws, size_t ws_size,
                              hipStream_t stream) {
    const float* x = (const float*)d_in[0];
    float* out0 = (float*)d_out;          // x_pool        [BC,To,Do,Ho,Wo]
    float* out1 = out0 + N0;              // inds_spatial  [BC,T ,Do,Ho,Wo]
    float* out2 = out1 + N1;              // inds_temporal [BC,To,Do*Ho*Wo]

    const int block = 256;
    const int grid  = TOTAL_THREADS / block;  // 8192
    pool3d_fused_kernel<<<grid, block, 0, stream>>>(x, out0, out1, out2);
}

// Round 4
// 120.912 us; speedup vs baseline: 1.0458x; 1.0403x over previous
//
#include <hip/hip_runtime.h>
#include <math.h>

// x: [B=2, C=8, T=8, D=64, H=128, W=128] float32
constexpr int BC = 16;                 // B*C
constexpr int T  = 8,  D  = 64, H  = 128, W  = 128;
constexpr int To = 4,  Do = 32, Ho = 64,  Wo = 64;
constexpr int WQ = Wo / 2;             // each thread: one float4 = 2 output windows
constexpr int N0 = BC * To * Do * Ho * Wo;   // x_pool elems   (8388608)
constexpr int N1 = BC * T  * Do * Ho * Wo;   // inds_spatial   (16777216)
constexpr int TOTAL_THREADS = BC * To * Do * Ho * WQ;  // 4194304

typedef float f32x4 __attribute__((ext_vector_type(4)));
typedef float f32x2 __attribute__((ext_vector_type(2)));

__global__ __launch_bounds__(256)
void pool3d_fused_kernel(const float* __restrict__ x,
                         float* __restrict__ xpool,   // [BC,To,Do,Ho,Wo] f32
                         float* __restrict__ sidx,    // [BC,T ,Do,Ho,Wo] idx-as-f32
                         float* __restrict__ tidx)    // [BC,To,Do,Ho,Wo] idx-as-f32
{
    const int tid = blockIdx.x * 256 + threadIdx.x;   // grid is exact

    const int wq = tid & (WQ - 1);
    int r = tid / WQ;
    const int ho = r & (Ho - 1); r /= Ho;
    const int dd = r & (Do - 1); r /= Do;
    const int to = r & (To - 1); r /= To;
    const int bc = r;

    const int col = 4 * wq;

    // ---- Phase 1: issue ALL 8 loads (unit-stride 16B/lane, 1KB/wave/instr) ----
    f32x4 v[2][2][2];   // [j=t-slice][kd][kh]
    #pragma unroll
    for (int j = 0; j < 2; ++j) {
        const int t = 2 * to + j;
        const int tbase = ((bc * T + t) * D) * H * W;  // max 2^27, fits int32
        #pragma unroll
        for (int kd = 0; kd < 2; ++kd) {
            const int d = 2 * dd + kd;
            #pragma unroll
            for (int kh = 0; kh < 2; ++kh) {
                const int h = 2 * ho + kh;
                v[j][kd][kh] = *reinterpret_cast<const f32x4*>(
                    x + tbase + (d * H + h) * W + col);
            }
        }
    }

    // ---- Phase 2: spatial pool (first-max scan order kd,kh,kw; strict '>') ----
    float sv[2][2];
    int   si[2][2];
    #pragma unroll
    for (int j = 0; j < 2; ++j) {
        float b0 = -INFINITY, b1 = -INFINITY;
        int   i0 = 0,          i1 = 0;
        #pragma unroll
        for (int kd = 0; kd < 2; ++kd) {
            const int d = 2 * dd + kd;
            #pragma unroll
            for (int kh = 0; kh < 2; ++kh) {
                const int h  = 2 * ho + kh;
                const int ib = (d * H + h) * W + col;
                const f32x4 a = v[j][kd][kh];
                if (a.x > b0) { b0 = a.x; i0 = ib;     }
                if (a.y > b0) { b0 = a.y; i0 = ib + 1; }
                if (a.z > b1) { b1 = a.z; i1 = ib + 2; }
                if (a.w > b1) { b1 = a.w; i1 = ib + 3; }
            }
        }
        sv[j][0] = b0; sv[j][1] = b1;
        si[j][0] = i0; si[j][1] = i1;
    }

    // ---- Phase 3: temporal pool (tie keeps t0 -> strict '>') ----
    const int kt0 = (sv[1][0] > sv[0][0]) ? 1 : 0;
    const int kt1 = (sv[1][1] > sv[0][1]) ? 1 : 0;

    // ---- Phase 4: all stores at the end (contiguous per wave, nt hint) ----
    f32x2 s0; s0.x = (float)si[0][0]; s0.y = (float)si[0][1];
    f32x2 s1; s1.x = (float)si[1][0]; s1.y = (float)si[1][1];
    const int sbase = ((bc * T + 2 * to) * Do + dd) * Ho * Wo + ho * Wo + 2 * wq;
    constexpr int tstride = Do * Ho * Wo;  // one t-slice of sidx
    __builtin_nontemporal_store(s0, reinterpret_cast<f32x2*>(sidx + sbase));
    __builtin_nontemporal_store(s1, reinterpret_cast<f32x2*>(sidx + sbase + tstride));

    f32x2 ov; ov.x = kt0 ? sv[1][0] : sv[0][0];
              ov.y = kt1 ? sv[1][1] : sv[0][1];
    f32x2 ot; ot.x = (float)(2 * to + kt0);
              ot.y = (float)(2 * to + kt1);
    const int oo = (((bc * To + to) * Do + dd) * Ho + ho) * Wo + 2 * wq;
    __builtin_nontemporal_store(ov, reinterpret_cast<f32x2*>(xpool + oo));
    __builtin_nontemporal_store(ot, reinterpret_cast<f32x2*>(tidx + oo));
}

extern "C" void kernel_launch(void* const* d_in, const int* in_sizes, int n_in,
                              void* d_out, int out_size, void* d_ws, size_t ws_size,
                              hipStream_t stream) {
    const float* x = (const float*)d_in[0];
    float* out0 = (float*)d_out;          // x_pool        [BC,To,Do,Ho,Wo]
    float* out1 = out0 + N0;              // inds_spatial  [BC,T ,Do,Ho,Wo]
    float* out2 = out1 + N1;              // inds_temporal [BC,To,Do*Ho*Wo]

    const int block = 256;
    const int grid  = TOTAL_THREADS / block;  // 16384
    pool3d_fused_kernel<<<grid, block, 0, stream>>>(x, out0, out1, out2);
}